// Round 1
// baseline (296.921 us; speedup 1.0000x reference)
//
#include <hip/hip_runtime.h>
#include <stdint.h>

#define DIM 1024
#define MOE_HID 512
#define SH_HID 2048
#define NE 16
#define NT 2048
#define ROWS_CAP 6144   // 4096 assignments + 16*128 max padding

typedef unsigned short u16;
typedef __attribute__((ext_vector_type(8))) short s16x8;
typedef __attribute__((ext_vector_type(4))) float f32x4;

__device__ __forceinline__ u16 f2bf(float f){
  union { float f; unsigned v; } x; x.f = f;
  unsigned r = x.v + 0x7FFF + ((x.v >> 16) & 1);
  return (u16)(r >> 16);
}

__device__ __forceinline__ void gld16(const void* g, void* l){
  __builtin_amdgcn_global_load_lds(
      (const __attribute__((address_space(1))) void*)g,
      (__attribute__((address_space(3))) void*)l, 16, 0, 0);
}

// ---------------- fp32 -> bf16 convert ----------------
__global__ void k_cvt(const float* __restrict__ s, u16* __restrict__ d, int n){
  int i = (blockIdx.x * 256 + threadIdx.x) * 4;
  int stride = gridDim.x * 256 * 4;
  for(; i < n; i += stride){
    float4 v = *(const float4*)(s + i);
    ushort4 o;
    o.x = f2bf(v.x); o.y = f2bf(v.y); o.z = f2bf(v.z); o.w = f2bf(v.w);
    *(ushort4*)(d + i) = o;
  }
}

// ---------------- router: logits (fp32), top-2, scores, shared-gate logit ----------------
__global__ void k_router(const float* __restrict__ x, const float* __restrict__ Wg,
                         const float* __restrict__ Wsgate1,
                         int* __restrict__ inds, float* __restrict__ scores,
                         float* __restrict__ gl, int* __restrict__ counts){
  int lane = threadIdx.x & 63;
  int t = blockIdx.x * 4 + (threadIdx.x >> 6);
  const float* xt = x + (size_t)t * DIM;
  float acc[NE];
#pragma unroll
  for(int e = 0; e < NE; e++) acc[e] = 0.f;
  float accs = 0.f;
  for(int j = 0; j < 16; j++){
    int d = lane + 64 * j;
    float xv = xt[d];
    accs += xv * Wsgate1[d];
#pragma unroll
    for(int e = 0; e < NE; e++) acc[e] += xv * Wg[e * DIM + d];
  }
#pragma unroll
  for(int off = 32; off; off >>= 1){
#pragma unroll
    for(int e = 0; e < NE; e++) acc[e] += __shfl_xor(acc[e], off, 64);
    accs += __shfl_xor(accs, off, 64);
  }
  if(lane == 0){
    int b0 = 0; float v0 = acc[0];
    for(int e = 1; e < NE; e++) if(acc[e] > v0){ v0 = acc[e]; b0 = e; }
    int b1 = (b0 == 0) ? 1 : 0; float v1 = acc[b1];
    for(int e = 0; e < NE; e++) if(e != b0 && acc[e] > v1){ v1 = acc[e]; b1 = e; }
    // top-2 renormalized softmax == 2-way softmax of the two top logits
    float s0 = 1.f / (1.f + expf(v1 - v0));
    inds[t*2+0] = b0; inds[t*2+1] = b1;
    scores[t*2+0] = s0; scores[t*2+1] = 1.f - s0;
    gl[t] = accs;
    atomicAdd(&counts[b0], 1);
    atomicAdd(&counts[b1], 1);
  }
}

// ---------------- prefix: padded per-expert offsets ----------------
__global__ void k_prefix(const int* __restrict__ counts, int* __restrict__ offs,
                         int* __restrict__ fill){
  if(threadIdx.x == 0){
    int o = 0;
    for(int e = 0; e < NE; e++){
      offs[e] = o;
      o += (counts[e] + 127) & ~127;
      fill[e] = 0;
    }
  }
}

// ---------------- scatter tokens into per-expert contiguous rows ----------------
__global__ void k_scatter(const u16* __restrict__ xb, const int* __restrict__ inds,
                          const float* __restrict__ scores, const int* __restrict__ offs,
                          int* __restrict__ fill, u16* __restrict__ Xp,
                          int* __restrict__ rowinfo, float* __restrict__ rowscore){
  int t = blockIdx.x;
  __shared__ int srow[2];
  if(threadIdx.x == 0){
#pragma unroll
    for(int k = 0; k < 2; k++){
      int e = inds[t*2+k];
      int row = offs[e] + atomicAdd(&fill[e], 1);
      srow[k] = row;
      rowinfo[row] = t*2+k;
      rowscore[row] = scores[t*2+k];
    }
  }
  __syncthreads();
  uint4 v = ((const uint4*)(xb + (size_t)t * DIM))[threadIdx.x];
#pragma unroll
  for(int k = 0; k < 2; k++)
    ((uint4*)(Xp + (size_t)srow[k] * DIM))[threadIdx.x] = v;
}

// ---------------- fused gate+up SwiGLU GEMM: H = silu(A@Bg^T) * (A@Bu^T) ----------------
// tile 128(M) x 64(N per matrix), K loop of 32. 4 waves (2x2), wave = 64x32.
__global__ __launch_bounds__(256, 2) void k_gateup(
    const u16* __restrict__ Abase, const u16* __restrict__ Bg_base,
    const u16* __restrict__ Bu_base, u16* __restrict__ Hbase,
    const int* __restrict__ counts, const int* __restrict__ offs, int shared_mode){
  __shared__ __align__(16) u16 As[128 * 32];
  __shared__ __align__(16) u16 Bgs[64 * 32];
  __shared__ __align__(16) u16 Bus[64 * 32];

  const int tid = threadIdx.x;
  const int lane = tid & 63, wid = tid >> 6;
  const int wm = wid >> 1, wn = wid & 1;
  const int mtile = blockIdx.y;
  const int n0 = blockIdx.x * 64;

  const u16 *A, *Bg, *Bu; u16* H; int ldh;
  if(shared_mode){
    A = Abase + (size_t)mtile * 128 * DIM;
    Bg = Bg_base; Bu = Bu_base;
    H = Hbase + (size_t)mtile * 128 * SH_HID;
    ldh = SH_HID;
  } else {
    int e = blockIdx.z;
    int M = counts[e];
    if(mtile * 128 >= M) return;
    int ro = offs[e];
    A = Abase + ((size_t)ro + (size_t)mtile * 128) * DIM;
    Bg = Bg_base + (size_t)e * MOE_HID * DIM;
    Bu = Bu_base + (size_t)e * MOE_HID * DIM;
    H = Hbase + ((size_t)ro + (size_t)mtile * 128) * MOE_HID;
    ldh = MOE_HID;
  }

  const int srow = tid >> 2;          // 0..63
  const int sk   = (tid & 3) * 8;     // k element offset
  u16* AsB1 = As  + wid * 512;
  u16* AsB2 = As  + 2048 + wid * 512;
  u16* BgB  = Bgs + wid * 512;
  u16* BuB  = Bus + wid * 512;

  f32x4 accg[4][2], accu[4][2];
#pragma unroll
  for(int m = 0; m < 4; m++)
#pragma unroll
    for(int n = 0; n < 2; n++){
      accg[m][n] = (f32x4){0.f,0.f,0.f,0.f};
      accu[m][n] = (f32x4){0.f,0.f,0.f,0.f};
    }

  const int fr = lane & 15;
  const int fk = (lane >> 4) * 8;

  for(int kt = 0; kt < DIM; kt += 32){
    gld16(A  + (size_t)srow * DIM + kt + sk, AsB1);
    gld16(A  + (size_t)(64 + srow) * DIM + kt + sk, AsB2);
    gld16(Bg + (size_t)(n0 + srow) * DIM + kt + sk, BgB);
    gld16(Bu + (size_t)(n0 + srow) * DIM + kt + sk, BuB);
    asm volatile("s_waitcnt vmcnt(0)" ::: "memory");
    __syncthreads();

    s16x8 af[4], bgf[2], buf2[2];
#pragma unroll
    for(int m = 0; m < 4; m++)
      af[m] = *(const s16x8*)(As + (wm*64 + m*16 + fr) * 32 + fk);
#pragma unroll
    for(int n = 0; n < 2; n++){
      bgf[n]  = *(const s16x8*)(Bgs + (wn*32 + n*16 + fr) * 32 + fk);
      buf2[n] = *(const s16x8*)(Bus + (wn*32 + n*16 + fr) * 32 + fk);
    }
#pragma unroll
    for(int m = 0; m < 4; m++)
#pragma unroll
      for(int n = 0; n < 2; n++){
        accg[m][n] = __builtin_amdgcn_mfma_f32_16x16x32_bf16(af[m], bgf[n], accg[m][n], 0, 0, 0);
        accu[m][n] = __builtin_amdgcn_mfma_f32_16x16x32_bf16(af[m], buf2[n], accu[m][n], 0, 0, 0);
      }
    __syncthreads();
  }

#pragma unroll
  for(int m = 0; m < 4; m++)
#pragma unroll
    for(int n = 0; n < 2; n++)
#pragma unroll
      for(int i = 0; i < 4; i++){
        int r = wm*64 + m*16 + ((lane >> 4) << 2) + i;
        int c = n0 + wn*32 + n*16 + (lane & 15);
        float g = accg[m][n][i], u = accu[m][n][i];
        float h = (g / (1.f + __expf(-g))) * u;
        H[(size_t)r * ldh + c] = f2bf(h);
      }
}

// ---------------- down GEMM: O = A @ B^T  (expert: scatter score*y to slots) ----------------
// tile 128x128, 4 waves (2x2), wave = 64x64
__global__ __launch_bounds__(256, 2) void k_down(
    const u16* __restrict__ Abase, const u16* __restrict__ Bbase,
    float* __restrict__ Obase,
    const int* __restrict__ counts, const int* __restrict__ offs,
    const int* __restrict__ rowinfo, const float* __restrict__ rowscore,
    int K, int shared_mode){
  __shared__ __align__(16) u16 As[128 * 32];
  __shared__ __align__(16) u16 Bs[128 * 32];
  const int tid = threadIdx.x, lane = tid & 63, wid = tid >> 6;
  const int wm = wid >> 1, wn = wid & 1;
  const int mtile = blockIdx.y, n0 = blockIdx.x * 128;

  const u16 *A, *B; int M = NT, roff = 0;
  if(shared_mode){
    A = Abase + (size_t)mtile * 128 * K;
    B = Bbase;
  } else {
    int e = blockIdx.z;
    M = counts[e];
    if(mtile * 128 >= M) return;
    roff = offs[e] + mtile * 128;
    A = Abase + (size_t)roff * K;
    B = Bbase + (size_t)e * DIM * K;
  }

  const int srow = tid >> 2;
  const int sk   = (tid & 3) * 8;

  f32x4 acc[4][4];
#pragma unroll
  for(int m = 0; m < 4; m++)
#pragma unroll
    for(int n = 0; n < 4; n++) acc[m][n] = (f32x4){0.f,0.f,0.f,0.f};

  const int fr = lane & 15;
  const int fk = (lane >> 4) * 8;

  for(int kt = 0; kt < K; kt += 32){
    gld16(A + (size_t)srow * K + kt + sk, As + wid * 512);
    gld16(A + (size_t)(64 + srow) * K + kt + sk, As + 2048 + wid * 512);
    gld16(B + (size_t)(n0 + srow) * K + kt + sk, Bs + wid * 512);
    gld16(B + (size_t)(n0 + 64 + srow) * K + kt + sk, Bs + 2048 + wid * 512);
    asm volatile("s_waitcnt vmcnt(0)" ::: "memory");
    __syncthreads();

    s16x8 af[4], bf[4];
#pragma unroll
    for(int m = 0; m < 4; m++)
      af[m] = *(const s16x8*)(As + (wm*64 + m*16 + fr) * 32 + fk);
#pragma unroll
    for(int n = 0; n < 4; n++)
      bf[n] = *(const s16x8*)(Bs + (wn*64 + n*16 + fr) * 32 + fk);
#pragma unroll
    for(int m = 0; m < 4; m++)
#pragma unroll
      for(int n = 0; n < 4; n++)
        acc[m][n] = __builtin_amdgcn_mfma_f32_16x16x32_bf16(af[m], bf[n], acc[m][n], 0, 0, 0);
    __syncthreads();
  }

#pragma unroll
  for(int m = 0; m < 4; m++)
#pragma unroll
    for(int i = 0; i < 4; i++){
      int rl = wm*64 + m*16 + ((lane >> 4) << 2) + i;
      if(shared_mode){
        float* orow = Obase + (size_t)(mtile*128 + rl) * DIM + n0 + wn*64 + (lane & 15);
#pragma unroll
        for(int n = 0; n < 4; n++) orow[n*16] = acc[m][n][i];
      } else if(mtile*128 + rl < M){
        int ar = roff + rl;
        int slot = rowinfo[ar];
        float sc = rowscore[ar];
        float* orow = Obase + (size_t)slot * DIM + n0 + wn*64 + (lane & 15);
#pragma unroll
        for(int n = 0; n < 4; n++) orow[n*16] = sc * acc[m][n][i];
      }
    }
}

// ---------------- combine: out = yp0 + yp1 + sigmoid(gl) * shared ----------------
__global__ void k_combine(const float* __restrict__ yp, const float* __restrict__ Sh,
                          const float* __restrict__ gl, float* __restrict__ out){
  int idx = (blockIdx.x * 256 + threadIdx.x) * 4;
  int t = idx >> 10;
  int d = idx & 1023;
  float s = 1.f / (1.f + __expf(-gl[t]));
  float4 a = *(const float4*)(yp + (size_t)(t*2)   * DIM + d);
  float4 b = *(const float4*)(yp + (size_t)(t*2+1) * DIM + d);
  float4 c = *(const float4*)(Sh + idx);
  float4 o;
  o.x = a.x + b.x + s * c.x;
  o.y = a.y + b.y + s * c.y;
  o.z = a.z + b.z + s * c.z;
  o.w = a.w + b.w + s * c.w;
  *(float4*)(out + idx) = o;
}

extern "C" void kernel_launch(void* const* d_in, const int* in_sizes, int n_in,
                              void* d_out, int out_size, void* d_ws, size_t ws_size,
                              hipStream_t stream){
  const float* x    = (const float*)d_in[0];
  const float* Wg   = (const float*)d_in[1];
  const float* Weg  = (const float*)d_in[2];
  const float* Weu  = (const float*)d_in[3];
  const float* Wed  = (const float*)d_in[4];
  const float* Wsg  = (const float*)d_in[5];
  const float* Wsu  = (const float*)d_in[6];
  const float* Wsd  = (const float*)d_in[7];
  const float* Wg1  = (const float*)d_in[8];
  float* out = (float*)d_out;

  char* p = (char*)d_ws;
  u16* xb     = (u16*)p;  p += (size_t)NT * DIM * 2;
  u16* Wegb   = (u16*)p;  p += (size_t)NE * MOE_HID * DIM * 2;
  u16* Weub   = (u16*)p;  p += (size_t)NE * MOE_HID * DIM * 2;
  u16* Wedb   = (u16*)p;  p += (size_t)NE * DIM * MOE_HID * 2;
  u16* Wsgb   = (u16*)p;  p += (size_t)SH_HID * DIM * 2;
  u16* Wsub   = (u16*)p;  p += (size_t)SH_HID * DIM * 2;
  u16* Wsdb   = (u16*)p;  p += (size_t)DIM * SH_HID * 2;
  u16* Hs     = (u16*)p;  p += (size_t)NT * SH_HID * 2;
  float* Sh   = (float*)p; p += (size_t)NT * DIM * 4;
  u16* Xp     = (u16*)p;  p += (size_t)ROWS_CAP * DIM * 2;
  u16* Hm     = (u16*)p;  p += (size_t)ROWS_CAP * MOE_HID * 2;
  float* yp   = (float*)p; p += (size_t)NT * 2 * DIM * 4;
  int* inds   = (int*)p;  p += 4096 * 4;
  float* scores = (float*)p; p += 4096 * 4;
  float* gl   = (float*)p; p += NT * 4;
  int* counts = (int*)p;  p += 64;
  int* offs   = (int*)p;  p += 64;
  int* fill   = (int*)p;  p += 64;
  int* rowinfo = (int*)p; p += ROWS_CAP * 4;
  float* rowscore = (float*)p; p += ROWS_CAP * 4;

  hipMemsetAsync(counts, 0, 64, stream);

  k_cvt<<<2048, 256, 0, stream>>>(x,   xb,   NT * DIM);
  k_cvt<<<2048, 256, 0, stream>>>(Weg, Wegb, NE * MOE_HID * DIM);
  k_cvt<<<2048, 256, 0, stream>>>(Weu, Weub, NE * MOE_HID * DIM);
  k_cvt<<<2048, 256, 0, stream>>>(Wed, Wedb, NE * DIM * MOE_HID);
  k_cvt<<<2048, 256, 0, stream>>>(Wsg, Wsgb, SH_HID * DIM);
  k_cvt<<<2048, 256, 0, stream>>>(Wsu, Wsub, SH_HID * DIM);
  k_cvt<<<2048, 256, 0, stream>>>(Wsd, Wsdb, DIM * SH_HID);

  k_router<<<NT/4, 256, 0, stream>>>(x, Wg, Wg1, inds, scores, gl, counts);
  k_prefix<<<1, 64, 0, stream>>>(counts, offs, fill);
  k_scatter<<<NT, 128, 0, stream>>>(xb, inds, scores, offs, fill, Xp, rowinfo, rowscore);

  // expert path
  k_gateup<<<dim3(8, 16, 16), 256, 0, stream>>>(Xp, Wegb, Weub, Hm, counts, offs, 0);
  k_down<<<dim3(8, 16, 16), 256, 0, stream>>>(Hm, Wedb, yp, counts, offs, rowinfo, rowscore, MOE_HID, 0);

  // shared expert path
  k_gateup<<<dim3(32, 16, 1), 256, 0, stream>>>(xb, Wsgb, Wsub, Hs, counts, offs, 1);
  k_down<<<dim3(8, 16, 1), 256, 0, stream>>>(Hs, Wsdb, Sh, counts, offs, rowinfo, rowscore, SH_HID, 1);

  k_combine<<<2048, 256, 0, stream>>>(yp, Sh, gl, out);
}

// Round 2
// 268.544 us; speedup vs baseline: 1.1057x; 1.1057x over previous
//
#include <hip/hip_runtime.h>
#include <stdint.h>

#define DIM 1024
#define MOE_HID 512
#define SH_HID 2048
#define NE 16
#define NT 2048
#define ROWS_CAP 6144   // 4096 assignments + 16*128 max padding

typedef unsigned short u16;
typedef __attribute__((ext_vector_type(8))) short s16x8;
typedef __attribute__((ext_vector_type(4))) float f32x4;

__device__ __forceinline__ u16 f2bf(float f){
  union { float f; unsigned v; } x; x.f = f;
  unsigned r = x.v + 0x7FFF + ((x.v >> 16) & 1);
  return (u16)(r >> 16);
}

__device__ __forceinline__ void gld16(const void* g, void* l){
  __builtin_amdgcn_global_load_lds(
      (const __attribute__((address_space(1))) void*)g,
      (__attribute__((address_space(3))) void*)l, 16, 0, 0);
}

// ---------------- fused fp32 -> bf16 convert (all 7 tensors, 1 launch) ----------------
struct CvtArgs {
  const float* s[7];
  u16* d[7];
  unsigned end[7];   // cumulative element ends
  int* counts;       // zeroed by block 0 (consumed later by k_router)
};

__global__ void k_cvt_all(CvtArgs a){
  if(blockIdx.x == 0 && threadIdx.x < NE) a.counts[threadIdx.x] = 0;
  unsigned total = a.end[6];
  for(unsigned i = (blockIdx.x * 256 + threadIdx.x) * 4; i < total; i += gridDim.x * 256 * 4){
    unsigned base = 0;
#pragma unroll
    for(int s = 0; s < 7; s++){
      unsigned e = a.end[s];
      if(i < e){
        unsigned off = i - base;
        float4 v = *(const float4*)(a.s[s] + off);
        ushort4 o;
        o.x = f2bf(v.x); o.y = f2bf(v.y); o.z = f2bf(v.z); o.w = f2bf(v.w);
        *(ushort4*)(a.d[s] + off) = o;
        break;
      }
      base = e;
    }
  }
}

// ---------------- router: fp32 logits, top-2, scores, shared-gate logit ----------------
// one wave per token; float4 loads, full ILP, one butterfly reduce
__global__ void k_router(const float* __restrict__ x, const float* __restrict__ Wg,
                         const float* __restrict__ Wsgate1,
                         int* __restrict__ inds, float* __restrict__ scores,
                         float* __restrict__ gl, int* __restrict__ counts){
  int lane = threadIdx.x & 63;
  int t = blockIdx.x * 4 + (threadIdx.x >> 6);
  const float4* xt = (const float4*)(x + (size_t)t * DIM);
  float4 xv[4];
#pragma unroll
  for(int j = 0; j < 4; j++) xv[j] = xt[lane + 64 * j];

  float acc[NE + 1];
#pragma unroll
  for(int e = 0; e <= NE; e++) acc[e] = 0.f;

#pragma unroll
  for(int e = 0; e < NE; e++){
    const float4* wr = (const float4*)(Wg + (size_t)e * DIM);
#pragma unroll
    for(int j = 0; j < 4; j++){
      float4 w = wr[lane + 64 * j];
      acc[e] += xv[j].x * w.x + xv[j].y * w.y + xv[j].z * w.z + xv[j].w * w.w;
    }
  }
  {
    const float4* wr = (const float4*)Wsgate1;
#pragma unroll
    for(int j = 0; j < 4; j++){
      float4 w = wr[lane + 64 * j];
      acc[NE] += xv[j].x * w.x + xv[j].y * w.y + xv[j].z * w.z + xv[j].w * w.w;
    }
  }

#pragma unroll
  for(int off = 32; off; off >>= 1)
#pragma unroll
    for(int e = 0; e <= NE; e++) acc[e] += __shfl_xor(acc[e], off, 64);

  if(lane == 0){
    int b0 = 0; float v0 = acc[0];
    for(int e = 1; e < NE; e++) if(acc[e] > v0){ v0 = acc[e]; b0 = e; }
    int b1 = (b0 == 0) ? 1 : 0; float v1 = acc[b1];
    for(int e = 0; e < NE; e++) if(e != b0 && acc[e] > v1){ v1 = acc[e]; b1 = e; }
    // renormalized top-2 softmax == 2-way softmax of the two top logits
    float s0 = 1.f / (1.f + expf(v1 - v0));
    inds[t*2+0] = b0; inds[t*2+1] = b1;
    scores[t*2+0] = s0; scores[t*2+1] = 1.f - s0;
    gl[t] = acc[NE];
    atomicAdd(&counts[b0], 1);
    atomicAdd(&counts[b1], 1);
  }
}

// ---------------- prefix: padded per-expert offsets ----------------
__global__ void k_prefix(const int* __restrict__ counts, int* __restrict__ offs,
                         int* __restrict__ fill){
  if(threadIdx.x == 0){
    int o = 0;
    for(int e = 0; e < NE; e++){
      offs[e] = o;
      o += (counts[e] + 127) & ~127;
      fill[e] = 0;
    }
  }
}

// ---------------- scatter tokens into per-expert contiguous rows ----------------
__global__ void k_scatter(const u16* __restrict__ xb, const int* __restrict__ inds,
                          const float* __restrict__ scores, const int* __restrict__ offs,
                          int* __restrict__ fill, u16* __restrict__ Xp,
                          int* __restrict__ rowinfo, float* __restrict__ rowscore){
  int t = blockIdx.x;
  __shared__ int srow[2];
  if(threadIdx.x == 0){
#pragma unroll
    for(int k = 0; k < 2; k++){
      int e = inds[t*2+k];
      int row = offs[e] + atomicAdd(&fill[e], 1);
      srow[k] = row;
      rowinfo[row] = t*2+k;
      rowscore[row] = scores[t*2+k];
    }
  }
  __syncthreads();
  uint4 v = ((const uint4*)(xb + (size_t)t * DIM))[threadIdx.x];
#pragma unroll
  for(int k = 0; k < 2; k++)
    ((uint4*)(Xp + (size_t)srow[k] * DIM))[threadIdx.x] = v;
}

// ---------------- fused gate+up SwiGLU GEMM: H = silu(A@Bg^T) * (A@Bu^T) ----------------
// tile 128(M) x 64(N per matrix), K loop of 32. 4 waves (2x2), wave = 64x32.
__global__ __launch_bounds__(256, 2) void k_gateup(
    const u16* __restrict__ Abase, const u16* __restrict__ Bg_base,
    const u16* __restrict__ Bu_base, u16* __restrict__ Hbase,
    const int* __restrict__ counts, const int* __restrict__ offs, int shared_mode){
  __shared__ __align__(16) u16 As[128 * 32];
  __shared__ __align__(16) u16 Bgs[64 * 32];
  __shared__ __align__(16) u16 Bus[64 * 32];

  const int tid = threadIdx.x;
  const int lane = tid & 63, wid = tid >> 6;
  const int wm = wid >> 1, wn = wid & 1;
  const int mtile = blockIdx.y;
  const int n0 = blockIdx.x * 64;

  const u16 *A, *Bg, *Bu; u16* H; int ldh;
  if(shared_mode){
    A = Abase + (size_t)mtile * 128 * DIM;
    Bg = Bg_base; Bu = Bu_base;
    H = Hbase + (size_t)mtile * 128 * SH_HID;
    ldh = SH_HID;
  } else {
    int e = blockIdx.z;
    int M = counts[e];
    if(mtile * 128 >= M) return;
    int ro = offs[e];
    A = Abase + ((size_t)ro + (size_t)mtile * 128) * DIM;
    Bg = Bg_base + (size_t)e * MOE_HID * DIM;
    Bu = Bu_base + (size_t)e * MOE_HID * DIM;
    H = Hbase + ((size_t)ro + (size_t)mtile * 128) * MOE_HID;
    ldh = MOE_HID;
  }

  const int srow = tid >> 2;          // 0..63
  const int sk   = (tid & 3) * 8;     // k element offset
  u16* AsB1 = As  + wid * 512;
  u16* AsB2 = As  + 2048 + wid * 512;
  u16* BgB  = Bgs + wid * 512;
  u16* BuB  = Bus + wid * 512;

  f32x4 accg[4][2], accu[4][2];
#pragma unroll
  for(int m = 0; m < 4; m++)
#pragma unroll
    for(int n = 0; n < 2; n++){
      accg[m][n] = (f32x4){0.f,0.f,0.f,0.f};
      accu[m][n] = (f32x4){0.f,0.f,0.f,0.f};
    }

  const int fr = lane & 15;
  const int fk = (lane >> 4) * 8;

  for(int kt = 0; kt < DIM; kt += 32){
    gld16(A  + (size_t)srow * DIM + kt + sk, AsB1);
    gld16(A  + (size_t)(64 + srow) * DIM + kt + sk, AsB2);
    gld16(Bg + (size_t)(n0 + srow) * DIM + kt + sk, BgB);
    gld16(Bu + (size_t)(n0 + srow) * DIM + kt + sk, BuB);
    asm volatile("s_waitcnt vmcnt(0)" ::: "memory");
    __syncthreads();

    s16x8 af[4], bgf[2], buf2[2];
#pragma unroll
    for(int m = 0; m < 4; m++)
      af[m] = *(const s16x8*)(As + (wm*64 + m*16 + fr) * 32 + fk);
#pragma unroll
    for(int n = 0; n < 2; n++){
      bgf[n]  = *(const s16x8*)(Bgs + (wn*32 + n*16 + fr) * 32 + fk);
      buf2[n] = *(const s16x8*)(Bus + (wn*32 + n*16 + fr) * 32 + fk);
    }
#pragma unroll
    for(int m = 0; m < 4; m++)
#pragma unroll
      for(int n = 0; n < 2; n++){
        accg[m][n] = __builtin_amdgcn_mfma_f32_16x16x32_bf16(af[m], bgf[n], accg[m][n], 0, 0, 0);
        accu[m][n] = __builtin_amdgcn_mfma_f32_16x16x32_bf16(af[m], buf2[n], accu[m][n], 0, 0, 0);
      }
    __syncthreads();
  }

#pragma unroll
  for(int m = 0; m < 4; m++)
#pragma unroll
    for(int n = 0; n < 2; n++)
#pragma unroll
      for(int i = 0; i < 4; i++){
        int r = wm*64 + m*16 + ((lane >> 4) << 2) + i;
        int c = n0 + wn*32 + n*16 + (lane & 15);
        float g = accg[m][n][i], u = accu[m][n][i];
        float h = (g / (1.f + __expf(-g))) * u;
        H[(size_t)r * ldh + c] = f2bf(h);
      }
}

// ---------------- down GEMM: O = A @ B^T ----------------
// tile 128x128, 4 waves (2x2). Expert mode: scatter score*y to (token,k) slots.
// Shared mode: blockIdx.z selects K-half; writes partial to O0/O1 (combine sums).
__global__ __launch_bounds__(256, 2) void k_down(
    const u16* __restrict__ Abase, const u16* __restrict__ Bbase,
    float* __restrict__ O0, float* __restrict__ O1,
    const int* __restrict__ counts, const int* __restrict__ offs,
    const int* __restrict__ rowinfo, const float* __restrict__ rowscore,
    int ldK, int kspan, int shared_mode){
  __shared__ __align__(16) u16 As[128 * 32];
  __shared__ __align__(16) u16 Bs[128 * 32];
  const int tid = threadIdx.x, lane = tid & 63, wid = tid >> 6;
  const int wm = wid >> 1, wn = wid & 1;
  const int mtile = blockIdx.y, n0 = blockIdx.x * 128;

  const u16 *A, *B; int M = NT, roff = 0, kBeg = 0;
  float* O = O0;
  if(shared_mode){
    A = Abase + (size_t)mtile * 128 * ldK;
    B = Bbase;
    kBeg = blockIdx.z * kspan;
    if(blockIdx.z) O = O1;
  } else {
    int e = blockIdx.z;
    M = counts[e];
    if(mtile * 128 >= M) return;
    roff = offs[e] + mtile * 128;
    A = Abase + (size_t)roff * ldK;
    B = Bbase + (size_t)e * DIM * ldK;
  }
  const int kEnd = kBeg + kspan;

  const int srow = tid >> 2;
  const int sk   = (tid & 3) * 8;

  f32x4 acc[4][4];
#pragma unroll
  for(int m = 0; m < 4; m++)
#pragma unroll
    for(int n = 0; n < 4; n++) acc[m][n] = (f32x4){0.f,0.f,0.f,0.f};

  const int fr = lane & 15;
  const int fk = (lane >> 4) * 8;

  for(int kt = kBeg; kt < kEnd; kt += 32){
    gld16(A + (size_t)srow * ldK + kt + sk, As + wid * 512);
    gld16(A + (size_t)(64 + srow) * ldK + kt + sk, As + 2048 + wid * 512);
    gld16(B + (size_t)(n0 + srow) * ldK + kt + sk, Bs + wid * 512);
    gld16(B + (size_t)(n0 + 64 + srow) * ldK + kt + sk, Bs + 2048 + wid * 512);
    asm volatile("s_waitcnt vmcnt(0)" ::: "memory");
    __syncthreads();

    s16x8 af[4], bf[4];
#pragma unroll
    for(int m = 0; m < 4; m++)
      af[m] = *(const s16x8*)(As + (wm*64 + m*16 + fr) * 32 + fk);
#pragma unroll
    for(int n = 0; n < 4; n++)
      bf[n] = *(const s16x8*)(Bs + (wn*64 + n*16 + fr) * 32 + fk);
#pragma unroll
    for(int m = 0; m < 4; m++)
#pragma unroll
      for(int n = 0; n < 4; n++)
        acc[m][n] = __builtin_amdgcn_mfma_f32_16x16x32_bf16(af[m], bf[n], acc[m][n], 0, 0, 0);
    __syncthreads();
  }

#pragma unroll
  for(int m = 0; m < 4; m++)
#pragma unroll
    for(int i = 0; i < 4; i++){
      int rl = wm*64 + m*16 + ((lane >> 4) << 2) + i;
      if(shared_mode){
        float* orow = O + (size_t)(mtile*128 + rl) * DIM + n0 + wn*64 + (lane & 15);
#pragma unroll
        for(int n = 0; n < 4; n++) orow[n*16] = acc[m][n][i];
      } else if(mtile*128 + rl < M){
        int ar = roff + rl;
        int slot = rowinfo[ar];
        float sc = rowscore[ar];
        float* orow = O0 + (size_t)slot * DIM + n0 + wn*64 + (lane & 15);
#pragma unroll
        for(int n = 0; n < 4; n++) orow[n*16] = sc * acc[m][n][i];
      }
    }
}

// ---------------- combine: out = yp0 + yp1 + sigmoid(gl) * (Sh0 + Sh1) ----------------
__global__ void k_combine(const float* __restrict__ yp, const float* __restrict__ Sh0,
                          const float* __restrict__ Sh1,
                          const float* __restrict__ gl, float* __restrict__ out){
  int idx = (blockIdx.x * 256 + threadIdx.x) * 4;
  int t = idx >> 10;
  int d = idx & 1023;
  float s = 1.f / (1.f + __expf(-gl[t]));
  float4 a = *(const float4*)(yp + (size_t)(t*2)   * DIM + d);
  float4 b = *(const float4*)(yp + (size_t)(t*2+1) * DIM + d);
  float4 c0 = *(const float4*)(Sh0 + idx);
  float4 c1 = *(const float4*)(Sh1 + idx);
  float4 o;
  o.x = a.x + b.x + s * (c0.x + c1.x);
  o.y = a.y + b.y + s * (c0.y + c1.y);
  o.z = a.z + b.z + s * (c0.z + c1.z);
  o.w = a.w + b.w + s * (c0.w + c1.w);
  *(float4*)(out + idx) = o;
}

extern "C" void kernel_launch(void* const* d_in, const int* in_sizes, int n_in,
                              void* d_out, int out_size, void* d_ws, size_t ws_size,
                              hipStream_t stream){
  const float* x    = (const float*)d_in[0];
  const float* Wg   = (const float*)d_in[1];
  const float* Weg  = (const float*)d_in[2];
  const float* Weu  = (const float*)d_in[3];
  const float* Wed  = (const float*)d_in[4];
  const float* Wsg  = (const float*)d_in[5];
  const float* Wsu  = (const float*)d_in[6];
  const float* Wsd  = (const float*)d_in[7];
  const float* Wg1  = (const float*)d_in[8];
  float* out = (float*)d_out;

  char* p = (char*)d_ws;
  u16* xb     = (u16*)p;  p += (size_t)NT * DIM * 2;
  u16* Wegb   = (u16*)p;  p += (size_t)NE * MOE_HID * DIM * 2;
  u16* Weub   = (u16*)p;  p += (size_t)NE * MOE_HID * DIM * 2;
  u16* Wedb   = (u16*)p;  p += (size_t)NE * DIM * MOE_HID * 2;
  u16* Wsgb   = (u16*)p;  p += (size_t)SH_HID * DIM * 2;
  u16* Wsub   = (u16*)p;  p += (size_t)SH_HID * DIM * 2;
  u16* Wsdb   = (u16*)p;  p += (size_t)DIM * SH_HID * 2;
  u16* Hs     = (u16*)p;  p += (size_t)NT * SH_HID * 2;
  float* Sh0  = (float*)p; p += (size_t)NT * DIM * 4;
  float* Sh1  = (float*)p; p += (size_t)NT * DIM * 4;
  u16* Xp     = (u16*)p;  p += (size_t)ROWS_CAP * DIM * 2;
  u16* Hm     = (u16*)p;  p += (size_t)ROWS_CAP * MOE_HID * 2;
  float* yp   = (float*)p; p += (size_t)NT * 2 * DIM * 4;
  int* inds   = (int*)p;  p += 4096 * 4;
  float* scores = (float*)p; p += 4096 * 4;
  float* gl   = (float*)p; p += NT * 4;
  int* counts = (int*)p;  p += 64;
  int* offs   = (int*)p;  p += 64;
  int* fill   = (int*)p;  p += 64;
  int* rowinfo = (int*)p; p += ROWS_CAP * 4;
  float* rowscore = (float*)p; p += ROWS_CAP * 4;

  CvtArgs ca;
  ca.s[0] = x;   ca.d[0] = xb;
  ca.s[1] = Weg; ca.d[1] = Wegb;
  ca.s[2] = Weu; ca.d[2] = Weub;
  ca.s[3] = Wed; ca.d[3] = Wedb;
  ca.s[4] = Wsg; ca.d[4] = Wsgb;
  ca.s[5] = Wsu; ca.d[5] = Wsub;
  ca.s[6] = Wsd; ca.d[6] = Wsdb;
  unsigned sizes[7] = { NT*DIM, NE*MOE_HID*DIM, NE*MOE_HID*DIM, NE*DIM*MOE_HID,
                        SH_HID*DIM, SH_HID*DIM, DIM*SH_HID };
  unsigned cum = 0;
  for(int i = 0; i < 7; i++){ cum += sizes[i]; ca.end[i] = cum; }
  ca.counts = counts;

  k_cvt_all<<<2048, 256, 0, stream>>>(ca);

  k_router<<<NT/4, 256, 0, stream>>>(x, Wg, Wg1, inds, scores, gl, counts);
  k_prefix<<<1, 64, 0, stream>>>(counts, offs, fill);
  k_scatter<<<NT, 128, 0, stream>>>(xb, inds, scores, offs, fill, Xp, rowinfo, rowscore);

  // expert path
  k_gateup<<<dim3(8, 16, 16), 256, 0, stream>>>(Xp, Wegb, Weub, Hm, counts, offs, 0);
  k_down<<<dim3(8, 16, 16), 256, 0, stream>>>(Hm, Wedb, yp, yp, counts, offs,
                                              rowinfo, rowscore, MOE_HID, MOE_HID, 0);

  // shared expert path (down split over K via blockIdx.z)
  k_gateup<<<dim3(32, 16, 1), 256, 0, stream>>>(xb, Wsgb, Wsub, Hs, counts, offs, 1);
  k_down<<<dim3(8, 16, 2), 256, 0, stream>>>(Hs, Wsdb, Sh0, Sh1, counts, offs,
                                             rowinfo, rowscore, SH_HID, SH_HID/2, 1);

  k_combine<<<2048, 256, 0, stream>>>(yp, Sh0, Sh1, gl, out);
}

// Round 3
// 182.745 us; speedup vs baseline: 1.6248x; 1.4695x over previous
//
#include <hip/hip_runtime.h>
#include <stdint.h>

#define DIM 1024
#define MOE_HID 512
#define SH_HID 2048
#define NE 16
#define NT 2048
#define ROWS_CAP 6144   // 4096 assignments + 16*127 max padding

typedef unsigned short u16;
typedef __attribute__((ext_vector_type(8))) short s16x8;
typedef __attribute__((ext_vector_type(4))) float f32x4;

__device__ __forceinline__ u16 f2bf(float f){
  union { float f; unsigned v; } x; x.f = f;
  unsigned r = x.v + 0x7FFF + ((x.v >> 16) & 1);
  return (u16)(r >> 16);
}

__device__ __forceinline__ void gld16(const void* g, void* l){
  __builtin_amdgcn_global_load_lds(
      (const __attribute__((address_space(1))) void*)g,
      (__attribute__((address_space(3))) void*)l, 16, 0, 0);
}

// ---------------- fused fp32 -> bf16 convert (all 7 tensors, 1 launch) ----------------
struct CvtArgs {
  const float* s[7];
  u16* d[7];
  unsigned end[7];   // cumulative element ends
};

__global__ void k_cvt_all(CvtArgs a){
  unsigned total = a.end[6];
  for(unsigned i = (blockIdx.x * 256 + threadIdx.x) * 4; i < total; i += gridDim.x * 256 * 4){
    unsigned base = 0;
#pragma unroll
    for(int s = 0; s < 7; s++){
      unsigned e = a.end[s];
      if(i < e){
        unsigned off = i - base;
        float4 v = *(const float4*)(a.s[s] + off);
        ushort4 o;
        o.x = f2bf(v.x); o.y = f2bf(v.y); o.z = f2bf(v.z); o.w = f2bf(v.w);
        *(ushort4*)(a.d[s] + off) = o;
        break;
      }
      base = e;
    }
  }
}

// ---------------- router: fp32 logits, top-2, scores, shared-gate logit ----------------
// one wave per token; float4 loads, full ILP, butterfly reduce. NO global atomics.
__global__ void k_router(const float* __restrict__ x, const float* __restrict__ Wg,
                         const float* __restrict__ Wsgate1,
                         int* __restrict__ inds, float* __restrict__ scores,
                         float* __restrict__ gl){
  int lane = threadIdx.x & 63;
  int t = blockIdx.x * 4 + (threadIdx.x >> 6);
  const float4* xt = (const float4*)(x + (size_t)t * DIM);
  float4 xv[4];
#pragma unroll
  for(int j = 0; j < 4; j++) xv[j] = xt[lane + 64 * j];

  float acc[NE + 1];
#pragma unroll
  for(int e = 0; e <= NE; e++) acc[e] = 0.f;

#pragma unroll
  for(int e = 0; e < NE; e++){
    const float4* wr = (const float4*)(Wg + (size_t)e * DIM);
#pragma unroll
    for(int j = 0; j < 4; j++){
      float4 w = wr[lane + 64 * j];
      acc[e] += xv[j].x * w.x + xv[j].y * w.y + xv[j].z * w.z + xv[j].w * w.w;
    }
  }
  {
    const float4* wr = (const float4*)Wsgate1;
#pragma unroll
    for(int j = 0; j < 4; j++){
      float4 w = wr[lane + 64 * j];
      acc[NE] += xv[j].x * w.x + xv[j].y * w.y + xv[j].z * w.z + xv[j].w * w.w;
    }
  }

#pragma unroll
  for(int off = 32; off; off >>= 1)
#pragma unroll
    for(int e = 0; e <= NE; e++) acc[e] += __shfl_xor(acc[e], off, 64);

  if(lane == 0){
    int b0 = 0; float v0 = acc[0];
    for(int e = 1; e < NE; e++) if(acc[e] > v0){ v0 = acc[e]; b0 = e; }
    int b1 = (b0 == 0) ? 1 : 0; float v1 = acc[b1];
    for(int e = 0; e < NE; e++) if(e != b0 && acc[e] > v1){ v1 = acc[e]; b1 = e; }
    // renormalized top-2 softmax == 2-way softmax of the two top logits
    float s0 = 1.f / (1.f + __expf(v1 - v0));
    inds[t*2+0] = b0; inds[t*2+1] = b1;
    scores[t*2+0] = s0; scores[t*2+1] = 1.f - s0;
    gl[t] = acc[NE];
  }
}

// ---------------- assign: histogram + padded prefix + row assignment (1 block, LDS atomics) ----------------
__global__ void k_assign(const int* __restrict__ inds, const float* __restrict__ scores,
                         int* __restrict__ counts, int* __restrict__ offs,
                         int* __restrict__ tokrow, int* __restrict__ rowinfo,
                         float* __restrict__ rowscore){
  __shared__ int cnt[NE], off_s[NE], fill[NE];
  int tid = threadIdx.x;
  if(tid < NE){ cnt[tid] = 0; fill[tid] = 0; }
  __syncthreads();
  int ea[4];
#pragma unroll
  for(int i = 0; i < 4; i++){
    int a = tid + 1024 * i;
    ea[i] = inds[a];
    atomicAdd(&cnt[ea[i]], 1);
  }
  __syncthreads();
  if(tid == 0){
    int o = 0;
    for(int e = 0; e < NE; e++){ off_s[e] = o; o += (cnt[e] + 127) & ~127; }
  }
  __syncthreads();
#pragma unroll
  for(int i = 0; i < 4; i++){
    int a = tid + 1024 * i;
    int e = ea[i];
    int row = off_s[e] + atomicAdd(&fill[e], 1);
    tokrow[a] = row;
    rowinfo[row] = a;
    rowscore[row] = scores[a];
  }
  if(tid < NE){ counts[tid] = cnt[tid]; offs[tid] = off_s[tid]; }
}

// ---------------- scatter tokens into per-expert contiguous rows ----------------
__global__ void k_scatter(const u16* __restrict__ xb, const int* __restrict__ tokrow,
                          u16* __restrict__ Xp){
  int t = blockIdx.x;
  int r0 = tokrow[t*2], r1 = tokrow[t*2+1];
  uint4 v = ((const uint4*)(xb + (size_t)t * DIM))[threadIdx.x];
  ((uint4*)(Xp + (size_t)r0 * DIM))[threadIdx.x] = v;
  ((uint4*)(Xp + (size_t)r1 * DIM))[threadIdx.x] = v;
}

// ---------------- fused gate+up SwiGLU GEMM: H = silu(A@Bg^T) * (A@Bu^T) ----------------
// tile 128(M) x 64(N per matrix), K loop of 32. 4 waves (2x2), wave = 64x32.
__global__ __launch_bounds__(256, 2) void k_gateup(
    const u16* __restrict__ Abase, const u16* __restrict__ Bg_base,
    const u16* __restrict__ Bu_base, u16* __restrict__ Hbase,
    const int* __restrict__ counts, const int* __restrict__ offs, int shared_mode){
  __shared__ __align__(16) u16 As[128 * 32];
  __shared__ __align__(16) u16 Bgs[64 * 32];
  __shared__ __align__(16) u16 Bus[64 * 32];

  const int tid = threadIdx.x;
  const int lane = tid & 63, wid = tid >> 6;
  const int wm = wid >> 1, wn = wid & 1;
  const int mtile = blockIdx.y;
  const int n0 = blockIdx.x * 64;

  const u16 *A, *Bg, *Bu; u16* H; int ldh;
  if(shared_mode){
    A = Abase + (size_t)mtile * 128 * DIM;
    Bg = Bg_base; Bu = Bu_base;
    H = Hbase + (size_t)mtile * 128 * SH_HID;
    ldh = SH_HID;
  } else {
    int e = blockIdx.z;
    int M = counts[e];
    if(mtile * 128 >= M) return;
    int ro = offs[e];
    A = Abase + ((size_t)ro + (size_t)mtile * 128) * DIM;
    Bg = Bg_base + (size_t)e * MOE_HID * DIM;
    Bu = Bu_base + (size_t)e * MOE_HID * DIM;
    H = Hbase + ((size_t)ro + (size_t)mtile * 128) * MOE_HID;
    ldh = MOE_HID;
  }

  const int srow = tid >> 2;          // 0..63
  const int sk   = (tid & 3) * 8;     // k element offset
  u16* AsB1 = As  + wid * 512;
  u16* AsB2 = As  + 2048 + wid * 512;
  u16* BgB  = Bgs + wid * 512;
  u16* BuB  = Bus + wid * 512;

  f32x4 accg[4][2], accu[4][2];
#pragma unroll
  for(int m = 0; m < 4; m++)
#pragma unroll
    for(int n = 0; n < 2; n++){
      accg[m][n] = (f32x4){0.f,0.f,0.f,0.f};
      accu[m][n] = (f32x4){0.f,0.f,0.f,0.f};
    }

  const int fr = lane & 15;
  const int fk = (lane >> 4) * 8;

  for(int kt = 0; kt < DIM; kt += 32){
    gld16(A  + (size_t)srow * DIM + kt + sk, AsB1);
    gld16(A  + (size_t)(64 + srow) * DIM + kt + sk, AsB2);
    gld16(Bg + (size_t)(n0 + srow) * DIM + kt + sk, BgB);
    gld16(Bu + (size_t)(n0 + srow) * DIM + kt + sk, BuB);
    asm volatile("s_waitcnt vmcnt(0)" ::: "memory");
    __syncthreads();

    s16x8 af[4], bgf[2], buf2[2];
#pragma unroll
    for(int m = 0; m < 4; m++)
      af[m] = *(const s16x8*)(As + (wm*64 + m*16 + fr) * 32 + fk);
#pragma unroll
    for(int n = 0; n < 2; n++){
      bgf[n]  = *(const s16x8*)(Bgs + (wn*32 + n*16 + fr) * 32 + fk);
      buf2[n] = *(const s16x8*)(Bus + (wn*32 + n*16 + fr) * 32 + fk);
    }
#pragma unroll
    for(int m = 0; m < 4; m++)
#pragma unroll
      for(int n = 0; n < 2; n++){
        accg[m][n] = __builtin_amdgcn_mfma_f32_16x16x32_bf16(af[m], bgf[n], accg[m][n], 0, 0, 0);
        accu[m][n] = __builtin_amdgcn_mfma_f32_16x16x32_bf16(af[m], buf2[n], accu[m][n], 0, 0, 0);
      }
    __syncthreads();
  }

#pragma unroll
  for(int m = 0; m < 4; m++)
#pragma unroll
    for(int n = 0; n < 2; n++)
#pragma unroll
      for(int i = 0; i < 4; i++){
        int r = wm*64 + m*16 + ((lane >> 4) << 2) + i;
        int c = n0 + wn*32 + n*16 + (lane & 15);
        float g = accg[m][n][i], u = accu[m][n][i];
        float h = (g / (1.f + __expf(-g))) * u;
        H[(size_t)r * ldh + c] = f2bf(h);
      }
}

// ---------------- down GEMM: O = A @ B^T ----------------
// tile 128x128, 4 waves (2x2). Expert mode: scatter score*y to (token,k) slots.
// Shared mode: blockIdx.z selects K-half; writes partial to O0/O1 (combine sums).
__global__ __launch_bounds__(256, 2) void k_down(
    const u16* __restrict__ Abase, const u16* __restrict__ Bbase,
    float* __restrict__ O0, float* __restrict__ O1,
    const int* __restrict__ counts, const int* __restrict__ offs,
    const int* __restrict__ rowinfo, const float* __restrict__ rowscore,
    int ldK, int kspan, int shared_mode){
  __shared__ __align__(16) u16 As[128 * 32];
  __shared__ __align__(16) u16 Bs[128 * 32];
  const int tid = threadIdx.x, lane = tid & 63, wid = tid >> 6;
  const int wm = wid >> 1, wn = wid & 1;
  const int mtile = blockIdx.y, n0 = blockIdx.x * 128;

  const u16 *A, *B; int M = NT, roff = 0, kBeg = 0;
  float* O = O0;
  if(shared_mode){
    A = Abase + (size_t)mtile * 128 * ldK;
    B = Bbase;
    kBeg = blockIdx.z * kspan;
    if(blockIdx.z) O = O1;
  } else {
    int e = blockIdx.z;
    M = counts[e];
    if(mtile * 128 >= M) return;
    roff = offs[e] + mtile * 128;
    A = Abase + (size_t)roff * ldK;
    B = Bbase + (size_t)e * DIM * ldK;
  }
  const int kEnd = kBeg + kspan;

  const int srow = tid >> 2;
  const int sk   = (tid & 3) * 8;

  f32x4 acc[4][4];
#pragma unroll
  for(int m = 0; m < 4; m++)
#pragma unroll
    for(int n = 0; n < 4; n++) acc[m][n] = (f32x4){0.f,0.f,0.f,0.f};

  const int fr = lane & 15;
  const int fk = (lane >> 4) * 8;

  for(int kt = kBeg; kt < kEnd; kt += 32){
    gld16(A + (size_t)srow * ldK + kt + sk, As + wid * 512);
    gld16(A + (size_t)(64 + srow) * ldK + kt + sk, As + 2048 + wid * 512);
    gld16(B + (size_t)(n0 + srow) * ldK + kt + sk, Bs + wid * 512);
    gld16(B + (size_t)(n0 + 64 + srow) * ldK + kt + sk, Bs + 2048 + wid * 512);
    asm volatile("s_waitcnt vmcnt(0)" ::: "memory");
    __syncthreads();

    s16x8 af[4], bf[4];
#pragma unroll
    for(int m = 0; m < 4; m++)
      af[m] = *(const s16x8*)(As + (wm*64 + m*16 + fr) * 32 + fk);
#pragma unroll
    for(int n = 0; n < 4; n++)
      bf[n] = *(const s16x8*)(Bs + (wn*64 + n*16 + fr) * 32 + fk);
#pragma unroll
    for(int m = 0; m < 4; m++)
#pragma unroll
      for(int n = 0; n < 4; n++)
        acc[m][n] = __builtin_amdgcn_mfma_f32_16x16x32_bf16(af[m], bf[n], acc[m][n], 0, 0, 0);
    __syncthreads();
  }

#pragma unroll
  for(int m = 0; m < 4; m++)
#pragma unroll
    for(int i = 0; i < 4; i++){
      int rl = wm*64 + m*16 + ((lane >> 4) << 2) + i;
      if(shared_mode){
        float* orow = O + (size_t)(mtile*128 + rl) * DIM + n0 + wn*64 + (lane & 15);
#pragma unroll
        for(int n = 0; n < 4; n++) orow[n*16] = acc[m][n][i];
      } else if(mtile*128 + rl < M){
        int ar = roff + rl;
        int slot = rowinfo[ar];
        float sc = rowscore[ar];
        float* orow = O0 + (size_t)slot * DIM + n0 + wn*64 + (lane & 15);
#pragma unroll
        for(int n = 0; n < 4; n++) orow[n*16] = sc * acc[m][n][i];
      }
    }
}

// ---------------- combine: out = yp0 + yp1 + sigmoid(gl) * (Sh0 + Sh1) ----------------
__global__ void k_combine(const float* __restrict__ yp, const float* __restrict__ Sh0,
                          const float* __restrict__ Sh1,
                          const float* __restrict__ gl, float* __restrict__ out){
  int idx = (blockIdx.x * 256 + threadIdx.x) * 4;
  int t = idx >> 10;
  int d = idx & 1023;
  float s = 1.f / (1.f + __expf(-gl[t]));
  float4 a = *(const float4*)(yp + (size_t)(t*2)   * DIM + d);
  float4 b = *(const float4*)(yp + (size_t)(t*2+1) * DIM + d);
  float4 c0 = *(const float4*)(Sh0 + idx);
  float4 c1 = *(const float4*)(Sh1 + idx);
  float4 o;
  o.x = a.x + b.x + s * (c0.x + c1.x);
  o.y = a.y + b.y + s * (c0.y + c1.y);
  o.z = a.z + b.z + s * (c0.z + c1.z);
  o.w = a.w + b.w + s * (c0.w + c1.w);
  *(float4*)(out + idx) = o;
}

extern "C" void kernel_launch(void* const* d_in, const int* in_sizes, int n_in,
                              void* d_out, int out_size, void* d_ws, size_t ws_size,
                              hipStream_t stream){
  const float* x    = (const float*)d_in[0];
  const float* Wg   = (const float*)d_in[1];
  const float* Weg  = (const float*)d_in[2];
  const float* Weu  = (const float*)d_in[3];
  const float* Wed  = (const float*)d_in[4];
  const float* Wsg  = (const float*)d_in[5];
  const float* Wsu  = (const float*)d_in[6];
  const float* Wsd  = (const float*)d_in[7];
  const float* Wg1  = (const float*)d_in[8];
  float* out = (float*)d_out;

  char* p = (char*)d_ws;
  u16* xb     = (u16*)p;  p += (size_t)NT * DIM * 2;
  u16* Wegb   = (u16*)p;  p += (size_t)NE * MOE_HID * DIM * 2;
  u16* Weub   = (u16*)p;  p += (size_t)NE * MOE_HID * DIM * 2;
  u16* Wedb   = (u16*)p;  p += (size_t)NE * DIM * MOE_HID * 2;
  u16* Wsgb   = (u16*)p;  p += (size_t)SH_HID * DIM * 2;
  u16* Wsub   = (u16*)p;  p += (size_t)SH_HID * DIM * 2;
  u16* Wsdb   = (u16*)p;  p += (size_t)DIM * SH_HID * 2;
  u16* Hs     = (u16*)p;  p += (size_t)NT * SH_HID * 2;
  float* Sh0  = (float*)p; p += (size_t)NT * DIM * 4;
  float* Sh1  = (float*)p; p += (size_t)NT * DIM * 4;
  u16* Xp     = (u16*)p;  p += (size_t)ROWS_CAP * DIM * 2;
  u16* Hm     = (u16*)p;  p += (size_t)ROWS_CAP * MOE_HID * 2;
  float* yp   = (float*)p; p += (size_t)NT * 2 * DIM * 4;
  int* inds   = (int*)p;  p += 4096 * 4;
  float* scores = (float*)p; p += 4096 * 4;
  float* gl   = (float*)p; p += NT * 4;
  int* counts = (int*)p;  p += 64;
  int* offs   = (int*)p;  p += 64;
  int* tokrow = (int*)p;  p += 4096 * 4;
  int* rowinfo = (int*)p; p += ROWS_CAP * 4;
  float* rowscore = (float*)p; p += ROWS_CAP * 4;

  CvtArgs ca;
  ca.s[0] = x;   ca.d[0] = xb;
  ca.s[1] = Weg; ca.d[1] = Wegb;
  ca.s[2] = Weu; ca.d[2] = Weub;
  ca.s[3] = Wed; ca.d[3] = Wedb;
  ca.s[4] = Wsg; ca.d[4] = Wsgb;
  ca.s[5] = Wsu; ca.d[5] = Wsub;
  ca.s[6] = Wsd; ca.d[6] = Wsdb;
  unsigned sizes[7] = { NT*DIM, NE*MOE_HID*DIM, NE*MOE_HID*DIM, NE*DIM*MOE_HID,
                        SH_HID*DIM, SH_HID*DIM, DIM*SH_HID };
  unsigned cum = 0;
  for(int i = 0; i < 7; i++){ cum += sizes[i]; ca.end[i] = cum; }

  k_cvt_all<<<2048, 256, 0, stream>>>(ca);

  k_router<<<NT/4, 256, 0, stream>>>(x, Wg, Wg1, inds, scores, gl);
  k_assign<<<1, 1024, 0, stream>>>(inds, scores, counts, offs, tokrow, rowinfo, rowscore);
  k_scatter<<<NT, 128, 0, stream>>>(xb, tokrow, Xp);

  // expert path
  k_gateup<<<dim3(8, 16, 16), 256, 0, stream>>>(Xp, Wegb, Weub, Hm, counts, offs, 0);
  k_down<<<dim3(8, 16, 16), 256, 0, stream>>>(Hm, Wedb, yp, yp, counts, offs,
                                              rowinfo, rowscore, MOE_HID, MOE_HID, 0);

  // shared expert path (down split over K via blockIdx.z)
  k_gateup<<<dim3(32, 16, 1), 256, 0, stream>>>(xb, Wsgb, Wsub, Hs, counts, offs, 1);
  k_down<<<dim3(8, 16, 2), 256, 0, stream>>>(Hs, Wsdb, Sh0, Sh1, counts, offs,
                                             rowinfo, rowscore, SH_HID, SH_HID/2, 1);

  k_combine<<<2048, 256, 0, stream>>>(yp, Sh0, Sh1, gl, out);
}